// Round 13
// baseline (146.365 us; speedup 1.0000x reference)
//
#include <hip/hip_runtime.h>
#include <math.h>

#define HID 128
#define CAP 12288                // padded edges per 256-node bucket
#define NBUCK_MAX 256
#define EPB 8192                 // edges per partA block

typedef _Float16 h2v __attribute__((ext_vector_type(2)));
typedef _Float16 h8v __attribute__((ext_vector_type(8)));
typedef float f4v __attribute__((ext_vector_type(4)));

static inline int ceil_div(int a, int b) { return (a + b - 1) / b; }

// ---------------- setup: transpose weights to fp16, init mask/bcur, zero accumulators ----------------

__global__ __launch_bounds__(256) void k_setup(const float* __restrict__ W1, const float* __restrict__ W2,
                                               const float* __restrict__ Wl, _Float16* T1, _Float16* T2,
                                               _Float16* Tl, unsigned int* mask, int* bcur,
                                               float* part, float* pcnt_raw, float* lsums, int mw, int NB) {
    int b = blockIdx.x;
    int t = threadIdx.x;
    if (b < 192) {
        int which = b >> 6;
        int idx = (b & 63) * 256 + t;
        int k = idx >> 7, c = idx & 127;
        const float* S = (which == 0) ? W1 : ((which == 1) ? W2 : Wl);
        _Float16* D = (which == 0) ? T1 : ((which == 1) ? T2 : Tl);
        D[c * 128 + k] = (_Float16)S[idx];
    } else {
        int i = (b - 192) * 256 + t;
        if (i < mw) mask[i] = 0u;
        if (i < NB) bcur[i] = i * CAP;
        if (b == 192) {
            if (t < 128) part[t] = 0.f;
            else if (t == 128) pcnt_raw[0] = 0.f;
            else if (t < 131) lsums[t - 129] = 0.f;
        }
    }
}

// ---------------- bucket partition with block-local counting sort + burst copy-out ----------------

__global__ __launch_bounds__(1024) void k_partA(const int* __restrict__ ei, int* __restrict__ bcur,
                                                unsigned int* __restrict__ ebuf,
                                                const int* __restrict__ batch, unsigned int* mask,
                                                int E, int B, int NB, int NBLKE) {
    if ((int)blockIdx.x >= NBLKE) {
        int i = ((int)blockIdx.x - NBLKE) * 1024 + threadIdx.x;
        if (i < B) { int nd = batch[i]; atomicOr(&mask[nd >> 5], 1u << (nd & 31)); }
        return;
    }
    __shared__ int lcnt[NBUCK_MAX];
    __shared__ int sc[NBUCK_MAX];
    __shared__ int lcur[NBUCK_MAX];
    __shared__ int gbase[NBUCK_MAX];
    __shared__ unsigned int se[EPB];
    int tid = threadIdx.x;
    if (tid < NBUCK_MAX) lcnt[tid] = 0;
    __syncthreads();
    int base = blockIdx.x * EPB;
    unsigned int pk[8];
    int bk[8];
#pragma unroll
    for (int j = 0; j < 8; ++j) {
        int e = base + tid + j * 1024;
        if (e < E) {
            int s = ei[e], d = ei[E + e];
            pk[j] = ((unsigned int)s << 8) | (unsigned int)(d & 255);
            bk[j] = d >> 8;
            atomicAdd(&lcnt[bk[j]], 1);
        } else bk[j] = -1;
    }
    __syncthreads();
    if (tid < NBUCK_MAX) sc[tid] = lcnt[tid];
    __syncthreads();
    for (int off = 1; off < NBUCK_MAX; off <<= 1) {
        int v = 0;
        if (tid < NBUCK_MAX && tid >= off) v = sc[tid - off];
        __syncthreads();
        if (tid < NBUCK_MAX) sc[tid] += v;
        __syncthreads();
    }
    if (tid < NBUCK_MAX) {
        int cc = lcnt[tid];
        int lo = sc[tid] - cc;
        lcur[tid] = lo;
        gbase[tid] = cc ? atomicAdd(&bcur[tid], cc) : 0;
    }
    __syncthreads();
#pragma unroll
    for (int j = 0; j < 8; ++j) {
        if (bk[j] >= 0) {
            int r = atomicAdd(&lcur[bk[j]], 1);
            se[r] = pk[j];
        }
    }
    __syncthreads();
    int wid = tid >> 6, lane = tid & 63;
    for (int b = wid; b < NB; b += 16) {
        int cc = lcnt[b];
        int lo = sc[b] - cc;
        int go = gbase[b];
        for (int i = lane; i < cc; i += 64) ebuf[go + i] = se[lo + i];
    }
}

// ---------------- one-pass CSR (pad to x8), no cast ----------------

__global__ __launch_bounds__(256) void k_csr(const unsigned int* __restrict__ ebuf, const int* __restrict__ bcur,
                                             const unsigned int* __restrict__ mask,
                                             float* __restrict__ sdinv, int* __restrict__ rs,
                                             int* __restrict__ degpk, unsigned int* __restrict__ csr, int N) {
    __shared__ unsigned int se[CAP];
    __shared__ int deg[256];
    __shared__ int fde[256];
    __shared__ int sc[256];
    __shared__ int cu[256];
    __shared__ int cf[256];
    int b = blockIdx.x, t = threadIdx.x;
    deg[t] = 0; fde[t] = 0;
    __syncthreads();
    int base = b * CAP;
    int ecnt = bcur[b] - base;
    for (int i = t; i < ecnt; i += 256) {
        unsigned int v = ebuf[base + i];
        int s = v >> 8;
        int fl = (mask[s >> 5] >> (s & 31)) & 1;
        se[i] = ((unsigned int)s << 9) | ((unsigned int)fl << 8) | (v & 255);
        atomicAdd(&deg[v & 255], 1);
        if (fl) atomicAdd(&fde[v & 255], 1);
    }
    __syncthreads();
    int dv = deg[t], fv = fde[t];
    int pv = (dv + 7) & ~7;
    sc[t] = pv;
    __syncthreads();
    for (int off = 1; off < 256; off <<= 1) {
        int v2 = (t >= off) ? sc[t - off] : 0;
        __syncthreads();
        sc[t] += v2;
        __syncthreads();
    }
    int r0 = base + sc[t] - pv;
    cu[t] = r0;
    cf[t] = r0 + (dv - fv);
    int node = b * 256 + t;
    if (node < N) {
        rs[node] = r0;
        degpk[node] = dv | (fv << 16);
        float di = rsqrtf((float)(dv + 1));
        if ((mask[node >> 5] >> (node & 31)) & 1) di = -di;
        sdinv[node] = di;
    }
    __syncthreads();
    for (int i = t; i < ecnt; i += 256) {
        unsigned int v = se[i];
        int d8 = v & 255;
        int p = ((v >> 8) & 1) ? atomicAdd(&cf[d8], 1) : atomicAdd(&cu[d8], 1);
        csr[p] = v >> 9;
    }
    if (node < N) {
        for (int j = dv; j < pv; ++j) csr[r0 + j] = (unsigned int)N;
    }
}

// ---------------- cast: xs = (half)(x * |dinv|), zero pad rows ----------------

__global__ __launch_bounds__(256) void k_cast(const float* __restrict__ x, const float* __restrict__ sdinv,
                                              _Float16* __restrict__ xs, _Float16* __restrict__ H, int N) {
    int i = blockIdx.x * 256 + threadIdx.x;     // each thread: 8 halves
    int nx = N * 16;
    if (i < nx) {
        int node = i >> 4;
        float da = fabsf(sdinv[node]);
        int o = i * 8;
        float4 a = *(const float4*)&x[o];
        float4 b = *(const float4*)&x[o + 4];
        h8v v;
        v[0] = (_Float16)(a.x * da); v[1] = (_Float16)(a.y * da);
        v[2] = (_Float16)(a.z * da); v[3] = (_Float16)(a.w * da);
        v[4] = (_Float16)(b.x * da); v[5] = (_Float16)(b.y * da);
        v[6] = (_Float16)(b.z * da); v[7] = (_Float16)(b.w * da);
        *(h8v*)&xs[o] = v;
    } else if (i < nx + 16) {
        *(h8v*)&xs[(size_t)i * 8] = (h8v){};                       // zero row ZN=N
    } else if (i < nx + 16 + 32) {
        int j = i - (nx + 16);
        *(h8v*)&H[(size_t)2 * N * HID + j * 8] = (h8v){};          // zero rows 2N, 2N+1
    }
}

// ---------------- fused layer 1 (512-thread / 32-node blocks): SpMM + MFMA (W1T in LDS) -> H ----------------
// 8 waves; spmm: 16-lane group per node (lg=0..31); MFMA: wave w -> rowtile (w&3)*16, colhalf (w>>2)*64.
// LDS 52.9 KB -> 3 blocks/CU = 24 waves/CU (2x the 256-thread variant at same sWT cost).

__global__ __launch_bounds__(512) void k_layer1(const _Float16* __restrict__ xs, const int* __restrict__ rs,
                                                const int* __restrict__ degpk, const unsigned int* __restrict__ csr,
                                                const float* __restrict__ sdinv, const _Float16* __restrict__ W1T,
                                                const float* __restrict__ bias, _Float16* __restrict__ H, int N) {
    __shared__ __align__(16) _Float16 sWT[128 * 136];   // 34816 B, overlaid by sC in epilogue
    __shared__ __align__(16) _Float16 sAgg[64 * 136];   // 17408 B
    __shared__ float sbias[128];
    __shared__ float sda[32];
    float* sC = (float*)sWT;                             // 64*132*4 = 33792 B <= 34816

    int tid = threadIdx.x;
    int wave = tid >> 6, lane = tid & 63;
    int grp = lane >> 4, rl = lane & 15;

#pragma unroll
    for (int it = 0; it < 4; ++it) {
        int lin = (it * 512 + tid) * 8;
        int c = lin >> 7, k = lin & 127;
        *(h8v*)&sWT[c * 136 + k] = *(const h8v*)&W1T[lin];
    }
    if (tid < 128) sbias[tid] = bias[tid];
    if (tid < 32) {
        int nd = blockIdx.x * 32 + tid;
        sda[tid] = (nd < N) ? fabsf(sdinv[nd]) : 0.f;
    }

    // ---- spmm phase (verified math incl. da row-norm) ----
    int ch = rl * 8;
    int lg = wave * 4 + grp;                 // 0..31
    int row = blockIdx.x * 32 + lg;
    bool ok = row < N;
    int p = 0, deg = 0, fd = 0;
    float sd = 0.f;
    h8v hs = {};
    if (ok) {
        p = rs[row];
        int dp = degpk[row];
        deg = dp & 0xffff; fd = dp >> 16;
        sd = sdinv[row];
        hs = *(const h8v*)&xs[(size_t)row * HID + ch];
    }
    int ud = deg - fd;
    int pd = (deg + 7) & ~7;
    int t1 = max(pd, __shfl_xor(pd, 16));
    int m  = max(t1, __shfl_xor(t1, 32));
    float U[8] = {}, F[8] = {};
    for (int i = 0; i < m; i += 16) {
        int id[16];
#pragma unroll
        for (int k = 0; k < 16; ++k) {
            int raw = (int)csr[p + i + k];
            id[k] = (i + k < pd) ? raw : N;
        }
        h8v h[16];
#pragma unroll
        for (int k = 0; k < 16; ++k) h[k] = *(const h8v*)&xs[(size_t)id[k] * HID + ch];
        h8v s0 = (h[0] + h[1]) + (h[2] + h[3]);
        h8v s1 = (h[4] + h[5]) + (h[6] + h[7]);
        h8v s2 = (h[8] + h[9]) + (h[10] + h[11]);
        h8v s3 = (h[12] + h[13]) + (h[14] + h[15]);
        h8v s  = (s0 + s1) + (s2 + s3);
#pragma unroll
        for (int j = 0; j < 8; ++j) U[j] += (float)s[j];
        if (i + 16 > ud) {
#pragma unroll
            for (int k = 0; k < 16; ++k) {
                if (i + k >= ud && i + k < deg) {
#pragma unroll
                    for (int j = 0; j < 8; ++j) F[j] += (float)h[k][j];
                }
            }
        }
    }
    {
        float da = fabsf(sd);
        float keep = (sd < 0.f) ? 0.f : 1.f;
        h8v lo = {}, hi = {};
        if (ok) {
#pragma unroll
            for (int j = 0; j < 8; ++j) {
                float f = (float)hs[j];
                lo[j] = (_Float16)(da * (U[j] + f));
                hi[j] = (_Float16)(da * (U[j] - F[j] + keep * f));
            }
        }
        *(h8v*)&sAgg[(2 * lg) * 136 + ch] = lo;
        *(h8v*)&sAgg[(2 * lg + 1) * 136 + ch] = hi;
    }
    __syncthreads();

    // ---- MFMA phase: 64 rows x 128 cols; wave w: rows (w&3)*16.., cols (w>>2)*64.. ----
    int g = lane >> 4;
    int rowtile = (wave & 3) * 16;
    int colbase = (wave >> 2) * 64;
    f4v acc[4];
#pragma unroll
    for (int cc = 0; cc < 4; ++cc) acc[cc] = (f4v){0.f, 0.f, 0.f, 0.f};
#pragma unroll
    for (int kb = 0; kb < 4; ++kb) {
        int k0 = kb * 32 + g * 8;
        h8v av = *(const h8v*)&sAgg[(rowtile + rl) * 136 + k0];
#pragma unroll
        for (int cc = 0; cc < 4; ++cc) {
            h8v bv = *(const h8v*)&sWT[(colbase + cc * 16 + rl) * 136 + k0];
            acc[cc] = __builtin_amdgcn_mfma_f32_16x16x32_f16(bv, av, acc[cc], 0, 0, 0);
        }
    }
    __syncthreads();   // sWT reads done; overlay as sC

    // ---- epilogue: bias+relu+dinv -> sC ----
    int lrow = rowtile + rl;                 // 0..63
    float dsc = sda[lrow >> 1];
#pragma unroll
    for (int cc = 0; cc < 4; ++cc) {
        f4v v = acc[cc];
        int col = colbase + cc * 16 + g * 4;
#pragma unroll
        for (int i2 = 0; i2 < 4; ++i2) v[i2] = fmaxf(v[i2] + sbias[col + i2], 0.f) * dsc;
        *(f4v*)&sC[lrow * 132 + col] = v;
    }
    __syncthreads();

    // ---- coalesced store: thread t -> row t>>3 (0..63), 16 cols ----
    int sr = tid >> 3, ck = tid & 7;
    int gRow = blockIdx.x * 64 + sr;
    if (gRow < 2 * N) {
        const float* src = &sC[sr * 132 + ck * 16];
        h8v o0, o1;
#pragma unroll
        for (int j = 0; j < 8; ++j) { o0[j] = (_Float16)src[j]; o1[j] = (_Float16)src[8 + j]; }
        _Float16* dst = &H[(size_t)gRow * HID + ck * 16];
        *(h8v*)&dst[0] = o0;
        *(h8v*)&dst[8] = o1;
    }
}

// ---------------- fused layer 2: batch SpMM + MFMA (W2T in LDS) -> gf/env, + fused pos-sum ----------------

__global__ __launch_bounds__(256) void k_layer2(const _Float16* __restrict__ H, const int* __restrict__ rs,
                                                const int* __restrict__ degpk, const unsigned int* __restrict__ csr,
                                                const float* __restrict__ sdinv, const int* __restrict__ batch,
                                                const int* __restrict__ labels,
                                                const _Float16* __restrict__ W2T, const float* __restrict__ bias,
                                                float* __restrict__ gf, _Float16* __restrict__ envh,
                                                float* __restrict__ yv, float* __restrict__ part,
                                                float* __restrict__ pcnt_raw, int B, int N) {
    __shared__ __align__(16) _Float16 sWT[128 * 136];
    __shared__ __align__(16) _Float16 sAgg[32 * 136];
    __shared__ float sbias[128];
    __shared__ float sy2[16];
    float* sC = (float*)sWT;

    int tid = threadIdx.x;
    int wave = tid >> 6, lane = tid & 63;
    int grp = lane >> 4, rl = lane & 15;

#pragma unroll
    for (int it = 0; it < 8; ++it) {
        int lin = (it * 256 + tid) * 8;
        int c = lin >> 7, k = lin & 127;
        *(h8v*)&sWT[c * 136 + k] = *(const h8v*)&W2T[lin];
    }
    if (tid < 128) sbias[tid] = bias[tid];

    int ch = rl * 8;
    int lg = wave * 4 + grp;
    int ri = blockIdx.x * 16 + lg;
    bool ok = ri < B;
    int p = 0, deg = 0, row = 0;
    float da = 0.f;
    h8v hn = {}, he = {};
    if (ok) {
        row = batch[ri];
        p = rs[row];
        deg = degpk[row] & 0xffff;
        da = fabsf(sdinv[row]);
        hn = *(const h8v*)&H[(size_t)row * 256 + ch];
        he = *(const h8v*)&H[(size_t)row * 256 + 128 + ch];
    }
    int pd = (deg + 7) & ~7;
    int t1 = max(pd, __shfl_xor(pd, 16));
    int m  = max(t1, __shfl_xor(t1, 32));
    float a[8] = {}, e[8] = {};
    for (int i = 0; i < m; i += 8) {
        int id[8];
#pragma unroll
        for (int k = 0; k < 8; ++k) {
            int raw = (int)csr[p + i + k];
            id[k] = (i + k < pd) ? raw : N;
        }
        h8v xn[8], xe[8];
#pragma unroll
        for (int k = 0; k < 8; ++k) {
            xn[k] = *(const h8v*)&H[(size_t)id[k] * 256 + ch];
            xe[k] = *(const h8v*)&H[(size_t)id[k] * 256 + 128 + ch];
        }
        h8v sn = ((xn[0] + xn[1]) + (xn[2] + xn[3])) + ((xn[4] + xn[5]) + (xn[6] + xn[7]));
        h8v sv = ((xe[0] + xe[1]) + (xe[2] + xe[3])) + ((xe[4] + xe[5]) + (xe[6] + xe[7]));
#pragma unroll
        for (int j = 0; j < 8; ++j) { a[j] += (float)sn[j]; e[j] += (float)sv[j]; }
    }
    {
        h8v lo = {}, hi = {};
        if (ok) {
#pragma unroll
            for (int j = 0; j < 8; ++j) {
                lo[j] = (_Float16)(da * (a[j] + (float)hn[j]));
                hi[j] = (_Float16)(da * (e[j] + (float)he[j]));
            }
        }
        *(h8v*)&sAgg[(2 * lg) * 136 + ch] = lo;
        *(h8v*)&sAgg[(2 * lg + 1) * 136 + ch] = hi;
    }
    __syncthreads();

    int g = lane >> 4;
    int rowtile = (wave & 1) * 16;
    int colbase = (wave >> 1) * 64;
    f4v acc[4];
#pragma unroll
    for (int cc = 0; cc < 4; ++cc) acc[cc] = (f4v){0.f, 0.f, 0.f, 0.f};
#pragma unroll
    for (int kb = 0; kb < 4; ++kb) {
        int k0 = kb * 32 + g * 8;
        h8v av = *(const h8v*)&sAgg[(rowtile + rl) * 136 + k0];
#pragma unroll
        for (int cc = 0; cc < 4; ++cc) {
            h8v bv = *(const h8v*)&sWT[(colbase + cc * 16 + rl) * 136 + k0];
            acc[cc] = __builtin_amdgcn_mfma_f32_16x16x32_f16(bv, av, acc[cc], 0, 0, 0);
        }
    }
    __syncthreads();

    int lrow = rowtile + rl;
#pragma unroll
    for (int cc = 0; cc < 4; ++cc) {
        f4v v = acc[cc];
        int col = colbase + cc * 16 + g * 4;
#pragma unroll
        for (int i2 = 0; i2 < 4; ++i2) v[i2] = fmaxf(v[i2] + sbias[col + i2], 0.f);
        *(f4v*)&sC[lrow * 132 + col] = v;
    }
    __syncthreads();

    int sr = tid >> 3, ck = tid & 7;
    int ri2 = blockIdx.x * 16 + (sr >> 1);
    if (ri2 < B) {
        const float* src = &sC[sr * 132 + ck * 16];
        if ((sr & 1) == 0) {
            float* dst = &gf[(size_t)ri2 * HID + ck * 16];
#pragma unroll
            for (int q = 0; q < 4; ++q) *(float4*)&dst[q * 4] = *(const float4*)&src[q * 4];
        } else {
            h8v o0, o1;
#pragma unroll
            for (int j = 0; j < 8; ++j) { o0[j] = (_Float16)src[j]; o1[j] = (_Float16)src[8 + j]; }
            _Float16* dst = &envh[(size_t)ri2 * HID + ck * 16];
            *(h8v*)&dst[0] = o0;
            *(h8v*)&dst[8] = o1;
        }
    }

    // ---- fused pos-sum ----
    int rr = blockIdx.x * 16 + tid;
    if (tid < 16) {
        float y = 0.f;
        if (rr < B) {
            y = (labels[batch[rr]] == 1) ? 1.f : 0.f;
            yv[rr] = y;
        }
        sy2[tid] = y;
    }
    __syncthreads();
    if (tid < 128) {
        float acc2 = 0.f;
#pragma unroll
        for (int r2 = 0; r2 < 16; ++r2) acc2 += sy2[r2] * sC[(2 * r2) * 132 + tid];
        atomicAdd(&part[tid], acc2);
    } else if (tid == 128) {
        float ps = 0.f;
#pragma unroll
        for (int r2 = 0; r2 < 16; ++r2) ps += sy2[r2];
        atomicAdd(&pcnt_raw[0], ps);
    }
}

// ---------------- ctxvec: v = Wctx @ (pos_sum / pos_cnt) ----------------

__global__ __launch_bounds__(128) void k_ctxvec(const float* __restrict__ Wctx, const float* __restrict__ part,
                                                const float* __restrict__ pcnt_raw, float* v) {
    __shared__ float sproto[128];
    int t = threadIdx.x;
    float pc = pcnt_raw[0];
    sproto[t] = part[t] / pc;
    __syncthreads();
    float acc = 0.f;
#pragma unroll 4
    for (int j = 0; j < 128; ++j) acc += Wctx[t * 128 + j] * sproto[j];
    v[t] = acc;
}

// ---------------- fused heads: T = env@Wloc (MFMA, in-register) + bilinear dots + loss partials ----------------

__global__ __launch_bounds__(256) void k_headsT(const _Float16* __restrict__ envh, const float* __restrict__ gf,
                                                const _Float16* __restrict__ WlT, const float* __restrict__ v,
                                                const float* __restrict__ yv, const float* __restrict__ bctx,
                                                const float* __restrict__ bloc, float* __restrict__ lsums, int B) {
    __shared__ __align__(16) _Float16 sWT[128 * 136];
    __shared__ float sv[128];
    int tid = threadIdx.x;
#pragma unroll
    for (int it = 0; it < 8; ++it) {
        int lin = (it * 256 + tid) * 8;
        int c = lin >> 7, k = lin & 127;
        *(h8v*)&sWT[c * 136 + k] = *(const h8v*)&WlT[lin];
    }
    if (tid < 128) sv[tid] = v[tid];
    __syncthreads();

    int wave = tid >> 6, lane = tid & 63;
    int rl = lane & 15, g = lane >> 4;
    int r = blockIdx.x * 64 + wave * 16 + rl;
    bool rok = r < B;
    f4v acc[8];
#pragma unroll
    for (int cf = 0; cf < 8; ++cf) acc[cf] = (f4v){0.f, 0.f, 0.f, 0.f};
#pragma unroll
    for (int kb = 0; kb < 4; ++kb) {
        int k0 = kb * 32 + g * 8;
        h8v av = {};
        if (rok) av = *(const h8v*)&envh[(size_t)r * HID + k0];
#pragma unroll
        for (int cf = 0; cf < 8; ++cf) {
            h8v bv = *(const h8v*)&sWT[(cf * 16 + rl) * 136 + k0];
            acc[cf] = __builtin_amdgcn_mfma_f32_16x16x32_f16(bv, av, acc[cf], 0, 0, 0);
        }
    }
    float s1 = 0.f, s2 = 0.f;
    if (rok) {
#pragma unroll
        for (int cf = 0; cf < 8; ++cf) {
            int col = cf * 16 + g * 4;
            float4 gv = *(const float4*)&gf[(size_t)r * HID + col];
            s2 += acc[cf][0] * gv.x + acc[cf][1] * gv.y + acc[cf][2] * gv.z + acc[cf][3] * gv.w;
            s1 += sv[col] * gv.x + sv[col + 1] * gv.y + sv[col + 2] * gv.z + sv[col + 3] * gv.w;
        }
    }
    s1 += __shfl_xor(s1, 16); s1 += __shfl_xor(s1, 32);
    s2 += __shfl_xor(s2, 16); s2 += __shfl_xor(s2, 32);
    float l1 = 0.f, l2 = 0.f;
    if (g == 0 && rok) {
        float y = yv[r];
        float z1 = s1 + bctx[0];
        float z2 = s2 + bloc[0];
        l1 = fmaxf(z1, 0.f) + log1pf(expf(-fabsf(z1))) - z1 * y;
        l2 = fmaxf(z2, 0.f) + log1pf(expf(-fabsf(z2))) - z2 * (1.f - y);
    }
#pragma unroll
    for (int o = 1; o < 64; o <<= 1) {
        l1 += __shfl_xor(l1, o);
        l2 += __shfl_xor(l2, o);
    }
    if (lane == 0) {
        atomicAdd(&lsums[0], l1);
        atomicAdd(&lsums[1], l2);
    }
}

__global__ void k_final(const float* __restrict__ lsums, const float* __restrict__ pcnt_raw,
                        float* out_loss, int B) {
    if (blockIdx.x == 0 && threadIdx.x == 0) {
        float pc = pcnt_raw[0];
        float nc = (float)B - pc;
        float total = 0.5f * (lsums[0] / (float)B) + 0.5f * (lsums[1] / (float)B);
        out_loss[0] = (pc > 0.f && nc > 0.f) ? total : 0.f;
    }
}

// ---------------- launcher ----------------

extern "C" void kernel_launch(void* const* d_in, const int* in_sizes, int n_in,
                              void* d_out, int out_size, void* d_ws, size_t ws_size,
                              hipStream_t stream) {
    const float* x      = (const float*)d_in[0];
    const int*   ei     = (const int*)d_in[1];
    const int*   batch  = (const int*)d_in[2];
    const int*   labels = (const int*)d_in[3];
    const float* W1     = (const float*)d_in[4];
    const float* b1     = (const float*)d_in[5];
    const float* W2     = (const float*)d_in[6];
    const float* b2     = (const float*)d_in[7];
    const float* Wctx   = (const float*)d_in[8];
    const float* bctx   = (const float*)d_in[9];
    const float* Wloc   = (const float*)d_in[10];
    const float* bloc   = (const float*)d_in[11];

    int N = in_sizes[0] / HID;
    int E = in_sizes[1] / 2;
    int B = in_sizes[2];
    float* out = (float*)d_out;

    char* wsb = (char*)d_ws;
    size_t off = 0;
    auto alloc = [&](size_t bytes) -> char* {
        char* p = wsb + off;
        off += (bytes + 255) & ~(size_t)255;
        return p;
    };
    int NB = ceil_div(N, 256);
    int mw = ceil_div(N, 32);

    _Float16* xs   = (_Float16*)alloc((size_t)(N + 1) * HID * 2);
    _Float16* H    = (_Float16*)alloc((size_t)(2 * N + 2) * HID * 2);
    unsigned int* ebuf = (unsigned int*)alloc((size_t)NB * CAP * 4);
    unsigned int* csr  = (unsigned int*)alloc((size_t)NB * CAP * 4);
    float* sdinv = (float*)alloc((size_t)N * 4);
    int*   rs    = (int*)alloc((size_t)N * 4);
    int*   degpk = (int*)alloc((size_t)N * 4);
    int*   bcur  = (int*)alloc((size_t)NB * 4);
    unsigned int* mask = (unsigned int*)alloc((size_t)mw * 4);
    _Float16* W1T = (_Float16*)alloc(128 * 128 * 2);
    _Float16* W2T = (_Float16*)alloc(128 * 128 * 2);
    _Float16* WlT = (_Float16*)alloc(128 * 128 * 2);
    _Float16* envh  = (_Float16*)alloc((size_t)B * HID * 2);
    float* yv    = (float*)alloc((size_t)B * 4);
    float* part  = (float*)alloc(128 * 4);
    float* pcnt_raw = (float*)alloc(256);
    float* lsums = (float*)alloc(256);
    float* vvec  = (float*)alloc(128 * 4);
    (void)ws_size; (void)n_in; (void)out_size;

    int NBLKE = ceil_div(E, EPB);
    int NBLKB = ceil_div(B, 1024);

    k_setup<<<192 + ceil_div(mw, 256), 256, 0, stream>>>(W1, W2, Wloc, W1T, W2T, WlT, mask, bcur,
                                                         part, pcnt_raw, lsums, mw, NB);
    k_partA<<<NBLKE + NBLKB, 1024, 0, stream>>>(ei, bcur, ebuf, batch, mask, E, B, NB, NBLKE);
    k_csr<<<NB, 256, 0, stream>>>(ebuf, bcur, mask, sdinv, rs, degpk, csr, N);
    k_cast<<<ceil_div(N * 16 + 48, 256), 256, 0, stream>>>(x, sdinv, xs, H, N);

    // fused layer 1 (512-thread / 32-node blocks)
    k_layer1<<<ceil_div(N, 32), 512, 0, stream>>>(xs, rs, degpk, csr, sdinv, W1T, b1, H, N);

    // fused layer 2 (+ pos-sum partials + yv)
    k_layer2<<<ceil_div(B, 16), 256, 0, stream>>>(H, rs, degpk, csr, sdinv, batch, labels, W2T, b2,
                                                  out, envh, yv, part, pcnt_raw, B, N);

    // heads
    k_ctxvec<<<1, 128, 0, stream>>>(Wctx, part, pcnt_raw, vvec);
    k_headsT<<<ceil_div(B, 64), 256, 0, stream>>>(envh, out, WlT, vvec, yv, bctx, bloc, lsums, B);
    k_final<<<1, 1, 0, stream>>>(lsums, pcnt_raw, out + (size_t)B * HID, B);
}

// Round 14
// 144.177 us; speedup vs baseline: 1.0152x; 1.0152x over previous
//
#include <hip/hip_runtime.h>
#include <math.h>

#define HID 128
#define CAP 12288                // padded edges per 256-node bucket
#define NBUCK_MAX 256
#define EPB 8192                 // edges per partA block

typedef _Float16 h2v __attribute__((ext_vector_type(2)));
typedef _Float16 h8v __attribute__((ext_vector_type(8)));
typedef float f4v __attribute__((ext_vector_type(4)));

static inline int ceil_div(int a, int b) { return (a + b - 1) / b; }

// ---------------- setup: transpose weights to fp16, init mask/bcur, zero accumulators ----------------

__global__ __launch_bounds__(256) void k_setup(const float* __restrict__ W1, const float* __restrict__ W2,
                                               const float* __restrict__ Wl, _Float16* T1, _Float16* T2,
                                               _Float16* Tl, unsigned int* mask, int* bcur,
                                               float* part, float* pcnt_raw, float* lsums, int* donecnt,
                                               int mw, int NB) {
    int b = blockIdx.x;
    int t = threadIdx.x;
    if (b < 192) {
        int which = b >> 6;
        int idx = (b & 63) * 256 + t;
        int k = idx >> 7, c = idx & 127;
        const float* S = (which == 0) ? W1 : ((which == 1) ? W2 : Wl);
        _Float16* D = (which == 0) ? T1 : ((which == 1) ? T2 : Tl);
        D[c * 128 + k] = (_Float16)S[idx];
    } else {
        int i = (b - 192) * 256 + t;
        if (i < mw) mask[i] = 0u;
        if (i < NB) bcur[i] = i * CAP;
        if (b == 192) {
            if (t < 128) part[t] = 0.f;
            else if (t == 128) pcnt_raw[0] = 0.f;
            else if (t < 131) lsums[t - 129] = 0.f;
            else if (t == 131) donecnt[0] = 0;
        }
    }
}

// ---------------- bucket partition with block-local counting sort + burst copy-out ----------------

__global__ __launch_bounds__(1024) void k_partA(const int* __restrict__ ei, int* __restrict__ bcur,
                                                unsigned int* __restrict__ ebuf,
                                                const int* __restrict__ batch, unsigned int* mask,
                                                int E, int B, int NB, int NBLKE) {
    if ((int)blockIdx.x >= NBLKE) {
        int i = ((int)blockIdx.x - NBLKE) * 1024 + threadIdx.x;
        if (i < B) { int nd = batch[i]; atomicOr(&mask[nd >> 5], 1u << (nd & 31)); }
        return;
    }
    __shared__ int lcnt[NBUCK_MAX];
    __shared__ int sc[NBUCK_MAX];
    __shared__ int lcur[NBUCK_MAX];
    __shared__ int gbase[NBUCK_MAX];
    __shared__ unsigned int se[EPB];
    int tid = threadIdx.x;
    if (tid < NBUCK_MAX) lcnt[tid] = 0;
    __syncthreads();
    int base = blockIdx.x * EPB;
    unsigned int pk[8];
    int bk[8];
#pragma unroll
    for (int j = 0; j < 8; ++j) {
        int e = base + tid + j * 1024;
        if (e < E) {
            int s = ei[e], d = ei[E + e];
            pk[j] = ((unsigned int)s << 8) | (unsigned int)(d & 255);
            bk[j] = d >> 8;
            atomicAdd(&lcnt[bk[j]], 1);
        } else bk[j] = -1;
    }
    __syncthreads();
    if (tid < NBUCK_MAX) sc[tid] = lcnt[tid];
    __syncthreads();
    for (int off = 1; off < NBUCK_MAX; off <<= 1) {
        int v = 0;
        if (tid < NBUCK_MAX && tid >= off) v = sc[tid - off];
        __syncthreads();
        if (tid < NBUCK_MAX) sc[tid] += v;
        __syncthreads();
    }
    if (tid < NBUCK_MAX) {
        int cc = lcnt[tid];
        int lo = sc[tid] - cc;
        lcur[tid] = lo;
        gbase[tid] = cc ? atomicAdd(&bcur[tid], cc) : 0;
    }
    __syncthreads();
#pragma unroll
    for (int j = 0; j < 8; ++j) {
        if (bk[j] >= 0) {
            int r = atomicAdd(&lcur[bk[j]], 1);
            se[r] = pk[j];
        }
    }
    __syncthreads();
    int wid = tid >> 6, lane = tid & 63;
    for (int b = wid; b < NB; b += 16) {
        int cc = lcnt[b];
        int lo = sc[b] - cc;
        int go = gbase[b];
        for (int i = lane; i < cc; i += 64) ebuf[go + i] = se[lo + i];
    }
}

// ---------------- one-pass CSR (pad to x8), no cast ----------------

__global__ __launch_bounds__(256) void k_csr(const unsigned int* __restrict__ ebuf, const int* __restrict__ bcur,
                                             const unsigned int* __restrict__ mask,
                                             float* __restrict__ sdinv, int* __restrict__ rs,
                                             int* __restrict__ degpk, unsigned int* __restrict__ csr, int N) {
    __shared__ unsigned int se[CAP];
    __shared__ int deg[256];
    __shared__ int fde[256];
    __shared__ int sc[256];
    __shared__ int cu[256];
    __shared__ int cf[256];
    int b = blockIdx.x, t = threadIdx.x;
    deg[t] = 0; fde[t] = 0;
    __syncthreads();
    int base = b * CAP;
    int ecnt = bcur[b] - base;
    for (int i = t; i < ecnt; i += 256) {
        unsigned int v = ebuf[base + i];
        int s = v >> 8;
        int fl = (mask[s >> 5] >> (s & 31)) & 1;
        se[i] = ((unsigned int)s << 9) | ((unsigned int)fl << 8) | (v & 255);
        atomicAdd(&deg[v & 255], 1);
        if (fl) atomicAdd(&fde[v & 255], 1);
    }
    __syncthreads();
    int dv = deg[t], fv = fde[t];
    int pv = (dv + 7) & ~7;
    sc[t] = pv;
    __syncthreads();
    for (int off = 1; off < 256; off <<= 1) {
        int v2 = (t >= off) ? sc[t - off] : 0;
        __syncthreads();
        sc[t] += v2;
        __syncthreads();
    }
    int r0 = base + sc[t] - pv;
    cu[t] = r0;
    cf[t] = r0 + (dv - fv);
    int node = b * 256 + t;
    if (node < N) {
        rs[node] = r0;
        degpk[node] = dv | (fv << 16);
        float di = rsqrtf((float)(dv + 1));
        if ((mask[node >> 5] >> (node & 31)) & 1) di = -di;
        sdinv[node] = di;
    }
    __syncthreads();
    for (int i = t; i < ecnt; i += 256) {
        unsigned int v = se[i];
        int d8 = v & 255;
        int p = ((v >> 8) & 1) ? atomicAdd(&cf[d8], 1) : atomicAdd(&cu[d8], 1);
        csr[p] = v >> 9;
    }
    if (node < N) {
        for (int j = dv; j < pv; ++j) csr[r0 + j] = (unsigned int)N;
    }
}

// ---------------- cast: xs = (half)(x * |dinv|), zero pad rows ----------------

__global__ __launch_bounds__(256) void k_cast(const float* __restrict__ x, const float* __restrict__ sdinv,
                                              _Float16* __restrict__ xs, _Float16* __restrict__ H, int N) {
    int i = blockIdx.x * 256 + threadIdx.x;     // each thread: 8 halves
    int nx = N * 16;
    if (i < nx) {
        int node = i >> 4;
        float da = fabsf(sdinv[node]);
        int o = i * 8;
        float4 a = *(const float4*)&x[o];
        float4 b = *(const float4*)&x[o + 4];
        h8v v;
        v[0] = (_Float16)(a.x * da); v[1] = (_Float16)(a.y * da);
        v[2] = (_Float16)(a.z * da); v[3] = (_Float16)(a.w * da);
        v[4] = (_Float16)(b.x * da); v[5] = (_Float16)(b.y * da);
        v[6] = (_Float16)(b.z * da); v[7] = (_Float16)(b.w * da);
        *(h8v*)&xs[o] = v;
    } else if (i < nx + 16) {
        *(h8v*)&xs[(size_t)i * 8] = (h8v){};                       // zero row ZN=N
    } else if (i < nx + 16 + 32) {
        int j = i - (nx + 16);
        *(h8v*)&H[(size_t)2 * N * HID + j * 8] = (h8v){};          // zero rows 2N, 2N+1
    }
}

// ---------------- fused layer 1 (512-thread / 32-node blocks): SpMM + MFMA (W1T in LDS) -> H ----------------

__global__ __launch_bounds__(512) void k_layer1(const _Float16* __restrict__ xs, const int* __restrict__ rs,
                                                const int* __restrict__ degpk, const unsigned int* __restrict__ csr,
                                                const float* __restrict__ sdinv, const _Float16* __restrict__ W1T,
                                                const float* __restrict__ bias, _Float16* __restrict__ H, int N) {
    __shared__ __align__(16) _Float16 sWT[128 * 136];   // 34816 B, overlaid by sC in epilogue
    __shared__ __align__(16) _Float16 sAgg[64 * 136];   // 17408 B
    __shared__ float sbias[128];
    __shared__ float sda[32];
    float* sC = (float*)sWT;                             // 64*132*4 = 33792 B <= 34816

    int tid = threadIdx.x;
    int wave = tid >> 6, lane = tid & 63;
    int grp = lane >> 4, rl = lane & 15;

#pragma unroll
    for (int it = 0; it < 4; ++it) {
        int lin = (it * 512 + tid) * 8;
        int c = lin >> 7, k = lin & 127;
        *(h8v*)&sWT[c * 136 + k] = *(const h8v*)&W1T[lin];
    }
    if (tid < 128) sbias[tid] = bias[tid];
    if (tid < 32) {
        int nd = blockIdx.x * 32 + tid;
        sda[tid] = (nd < N) ? fabsf(sdinv[nd]) : 0.f;
    }

    // ---- spmm phase (verified math incl. da row-norm) ----
    int ch = rl * 8;
    int lg = wave * 4 + grp;                 // 0..31
    int row = blockIdx.x * 32 + lg;
    bool ok = row < N;
    int p = 0, deg = 0, fd = 0;
    float sd = 0.f;
    h8v hs = {};
    if (ok) {
        p = rs[row];
        int dp = degpk[row];
        deg = dp & 0xffff; fd = dp >> 16;
        sd = sdinv[row];
        hs = *(const h8v*)&xs[(size_t)row * HID + ch];
    }
    int ud = deg - fd;
    int pd = (deg + 7) & ~7;
    int t1 = max(pd, __shfl_xor(pd, 16));
    int m  = max(t1, __shfl_xor(t1, 32));
    float U[8] = {}, F[8] = {};
    for (int i = 0; i < m; i += 16) {
        int id[16];
#pragma unroll
        for (int k = 0; k < 16; ++k) {
            int raw = (int)csr[p + i + k];
            id[k] = (i + k < pd) ? raw : N;
        }
        h8v h[16];
#pragma unroll
        for (int k = 0; k < 16; ++k) h[k] = *(const h8v*)&xs[(size_t)id[k] * HID + ch];
        h8v s0 = (h[0] + h[1]) + (h[2] + h[3]);
        h8v s1 = (h[4] + h[5]) + (h[6] + h[7]);
        h8v s2 = (h[8] + h[9]) + (h[10] + h[11]);
        h8v s3 = (h[12] + h[13]) + (h[14] + h[15]);
        h8v s  = (s0 + s1) + (s2 + s3);
#pragma unroll
        for (int j = 0; j < 8; ++j) U[j] += (float)s[j];
        if (i + 16 > ud) {
#pragma unroll
            for (int k = 0; k < 16; ++k) {
                if (i + k >= ud && i + k < deg) {
#pragma unroll
                    for (int j = 0; j < 8; ++j) F[j] += (float)h[k][j];
                }
            }
        }
    }
    {
        float da = fabsf(sd);
        float keep = (sd < 0.f) ? 0.f : 1.f;
        h8v lo = {}, hi = {};
        if (ok) {
#pragma unroll
            for (int j = 0; j < 8; ++j) {
                float f = (float)hs[j];
                lo[j] = (_Float16)(da * (U[j] + f));
                hi[j] = (_Float16)(da * (U[j] - F[j] + keep * f));
            }
        }
        *(h8v*)&sAgg[(2 * lg) * 136 + ch] = lo;
        *(h8v*)&sAgg[(2 * lg + 1) * 136 + ch] = hi;
    }
    __syncthreads();

    // ---- MFMA phase: 64 rows x 128 cols; wave w: rows (w&3)*16.., cols (w>>2)*64.. ----
    int g = lane >> 4;
    int rowtile = (wave & 3) * 16;
    int colbase = (wave >> 2) * 64;
    f4v acc[4];
#pragma unroll
    for (int cc = 0; cc < 4; ++cc) acc[cc] = (f4v){0.f, 0.f, 0.f, 0.f};
#pragma unroll
    for (int kb = 0; kb < 4; ++kb) {
        int k0 = kb * 32 + g * 8;
        h8v av = *(const h8v*)&sAgg[(rowtile + rl) * 136 + k0];
#pragma unroll
        for (int cc = 0; cc < 4; ++cc) {
            h8v bv = *(const h8v*)&sWT[(colbase + cc * 16 + rl) * 136 + k0];
            acc[cc] = __builtin_amdgcn_mfma_f32_16x16x32_f16(bv, av, acc[cc], 0, 0, 0);
        }
    }
    __syncthreads();   // sWT reads done; overlay as sC

    int lrow = rowtile + rl;                 // 0..63
    float dsc = sda[lrow >> 1];
#pragma unroll
    for (int cc = 0; cc < 4; ++cc) {
        f4v v = acc[cc];
        int col = colbase + cc * 16 + g * 4;
#pragma unroll
        for (int i2 = 0; i2 < 4; ++i2) v[i2] = fmaxf(v[i2] + sbias[col + i2], 0.f) * dsc;
        *(f4v*)&sC[lrow * 132 + col] = v;
    }
    __syncthreads();

    int sr = tid >> 3, ck = tid & 7;
    int gRow = blockIdx.x * 64 + sr;
    if (gRow < 2 * N) {
        const float* src = &sC[sr * 132 + ck * 16];
        h8v o0, o1;
#pragma unroll
        for (int j = 0; j < 8; ++j) { o0[j] = (_Float16)src[j]; o1[j] = (_Float16)src[8 + j]; }
        _Float16* dst = &H[(size_t)gRow * HID + ck * 16];
        *(h8v*)&dst[0] = o0;
        *(h8v*)&dst[8] = o1;
    }
}

// ---------------- fused layer 2 (512-thread / 16 batch rows): SpMM (32 lanes/row, view-split) + MFMA ----------------

__global__ __launch_bounds__(512) void k_layer2(const _Float16* __restrict__ H, const int* __restrict__ rs,
                                                const int* __restrict__ degpk, const unsigned int* __restrict__ csr,
                                                const float* __restrict__ sdinv, const int* __restrict__ batch,
                                                const int* __restrict__ labels,
                                                const _Float16* __restrict__ W2T, const float* __restrict__ bias,
                                                float* __restrict__ gf, _Float16* __restrict__ envh,
                                                float* __restrict__ yv, float* __restrict__ part,
                                                float* __restrict__ pcnt_raw, int B, int N) {
    __shared__ __align__(16) _Float16 sWT[128 * 136];   // 34816 B, overlaid by sC
    __shared__ __align__(16) _Float16 sAgg[32 * 136];   // 8704 B
    __shared__ float sbias[128];
    __shared__ float sy2[16];
    float* sC = (float*)sWT;                             // 32*132*4 = 16896 <= 34816

    int tid = threadIdx.x;
    int wave = tid >> 6, lane = tid & 63;

#pragma unroll
    for (int it = 0; it < 4; ++it) {
        int lin = (it * 512 + tid) * 8;
        int c = lin >> 7, k = lin & 127;
        *(h8v*)&sWT[c * 136 + k] = *(const h8v*)&W2T[lin];
    }
    if (tid < 128) sbias[tid] = bias[tid];

    // ---- spmm phase: 32 lanes per batch row; lane = one view x 8 channels ----
    int rl32 = lane & 31;
    int view = rl32 >> 4;
    int rl = rl32 & 15;
    int ch = rl * 8;
    int lg = wave * 2 + (lane >> 5);         // 0..15
    int ri = blockIdx.x * 16 + lg;
    bool ok = ri < B;
    int p = 0, deg = 0, row = 0;
    float da = 0.f;
    h8v hsv = {};
    if (ok) {
        row = batch[ri];
        p = rs[row];
        deg = degpk[row] & 0xffff;
        da = fabsf(sdinv[row]);
        hsv = *(const h8v*)&H[(size_t)row * 256 + view * 128 + ch];
    }
    int pd = (deg + 7) & ~7;
    int m = max(pd, __shfl_xor(pd, 32));
    float a[8] = {};
    for (int i = 0; i < m; i += 8) {
        int id[8];
#pragma unroll
        for (int k = 0; k < 8; ++k) {
            int raw = (int)csr[p + i + k];
            id[k] = (i + k < pd) ? raw : N;
        }
        h8v x[8];
#pragma unroll
        for (int k = 0; k < 8; ++k) x[k] = *(const h8v*)&H[(size_t)id[k] * 256 + view * 128 + ch];
        h8v s = ((x[0] + x[1]) + (x[2] + x[3])) + ((x[4] + x[5]) + (x[6] + x[7]));
#pragma unroll
        for (int j = 0; j < 8; ++j) a[j] += (float)s[j];
    }
    {
        h8v lo = {};
        if (ok) {
#pragma unroll
            for (int j = 0; j < 8; ++j) lo[j] = (_Float16)(da * (a[j] + (float)hsv[j]));
        }
        *(h8v*)&sAgg[(2 * lg + view) * 136 + ch] = lo;   // even = normal, odd = env
    }
    __syncthreads();

    // ---- MFMA: 32 rows x 128 cols; wave w: rows (w&1)*16, cols (w>>1)*32 (2 frags) ----
    int g = lane >> 4;
    int rl2 = lane & 15;
    int rowtile = (wave & 1) * 16;
    int colbase = (wave >> 1) * 32;
    f4v acc[2];
    acc[0] = (f4v){0.f, 0.f, 0.f, 0.f};
    acc[1] = (f4v){0.f, 0.f, 0.f, 0.f};
#pragma unroll
    for (int kb = 0; kb < 4; ++kb) {
        int k0 = kb * 32 + g * 8;
        h8v av = *(const h8v*)&sAgg[(rowtile + rl2) * 136 + k0];
#pragma unroll
        for (int cc = 0; cc < 2; ++cc) {
            h8v bv = *(const h8v*)&sWT[(colbase + cc * 16 + rl2) * 136 + k0];
            acc[cc] = __builtin_amdgcn_mfma_f32_16x16x32_f16(bv, av, acc[cc], 0, 0, 0);
        }
    }
    __syncthreads();   // sWT reads done; overlay as sC

    int lrow = rowtile + rl2;
#pragma unroll
    for (int cc = 0; cc < 2; ++cc) {
        f4v v = acc[cc];
        int col = colbase + cc * 16 + g * 4;
#pragma unroll
        for (int i2 = 0; i2 < 4; ++i2) v[i2] = fmaxf(v[i2] + sbias[col + i2], 0.f);
        *(f4v*)&sC[lrow * 132 + col] = v;
    }
    __syncthreads();

    // ---- split store: thread t -> local row t>>4 (0..31), 8 cols ----
    int sr = tid >> 4, ck = tid & 15;
    int ri2 = blockIdx.x * 16 + (sr >> 1);
    if (ri2 < B) {
        const float* src = &sC[sr * 132 + ck * 8];
        if ((sr & 1) == 0) {
            float* dst = &gf[(size_t)ri2 * HID + ck * 8];
            *(float4*)&dst[0] = *(const float4*)&src[0];
            *(float4*)&dst[4] = *(const float4*)&src[4];
        } else {
            h8v o;
#pragma unroll
            for (int j = 0; j < 8; ++j) o[j] = (_Float16)src[j];
            *(h8v*)&envh[(size_t)ri2 * HID + ck * 8] = o;
        }
    }

    // ---- fused pos-sum ----
    int rr = blockIdx.x * 16 + tid;
    if (tid < 16) {
        float y = 0.f;
        if (rr < B) {
            y = (labels[batch[rr]] == 1) ? 1.f : 0.f;
            yv[rr] = y;
        }
        sy2[tid] = y;
    }
    __syncthreads();
    if (tid < 128) {
        float acc2 = 0.f;
#pragma unroll
        for (int r2 = 0; r2 < 16; ++r2) acc2 += sy2[r2] * sC[(2 * r2) * 132 + tid];
        atomicAdd(&part[tid], acc2);
    } else if (tid == 128) {
        float ps = 0.f;
#pragma unroll
        for (int r2 = 0; r2 < 16; ++r2) ps += sy2[r2];
        atomicAdd(&pcnt_raw[0], ps);
    }
}

// ---------------- fused heads: ctxvec + T = env@Wloc (MFMA in-register) + bilinear dots + final ----------------

__global__ __launch_bounds__(256) void k_headsT(const _Float16* __restrict__ envh, const float* __restrict__ gf,
                                                const _Float16* __restrict__ WlT, const float* __restrict__ Wctx,
                                                const float* __restrict__ part, const float* __restrict__ pcnt_raw,
                                                const float* __restrict__ yv, const float* __restrict__ bctx,
                                                const float* __restrict__ bloc, float* __restrict__ lsums,
                                                int* __restrict__ donecnt, float* __restrict__ out_loss,
                                                int B, int nblk) {
    __shared__ __align__(16) _Float16 sWT[128 * 136];
    __shared__ float sv[128];
    __shared__ float sproto[128];
    int tid = threadIdx.x;
#pragma unroll
    for (int it = 0; it < 8; ++it) {
        int lin = (it * 256 + tid) * 8;
        int c = lin >> 7, k = lin & 127;
        *(h8v*)&sWT[c * 136 + k] = *(const h8v*)&WlT[lin];
    }
    if (tid < 128) sproto[tid] = part[tid] / pcnt_raw[0];
    __syncthreads();
    if (tid < 128) {
        float acc = 0.f;
#pragma unroll 4
        for (int j = 0; j < 128; ++j) acc += Wctx[tid * 128 + j] * sproto[j];
        sv[tid] = acc;
    }
    __syncthreads();

    int wave = tid >> 6, lane = tid & 63;
    int rl = lane & 15, g = lane >> 4;
    int r = blockIdx.x * 64 + wave * 16 + rl;
    bool rok = r < B;
    f4v acc[8];
#pragma unroll
    for (int cf = 0; cf < 8; ++cf) acc[cf] = (f4v){0.f, 0.f, 0.f, 0.f};
#pragma unroll
    for (int kb = 0; kb < 4; ++kb) {
        int k0 = kb * 32 + g * 8;
        h8v av = {};
        if (rok) av = *(const h8v*)&envh[(size_t)r * HID + k0];
#pragma unroll
        for (int cf = 0; cf < 8; ++cf) {
            h8v bv = *(const h8v*)&sWT[(cf * 16 + rl) * 136 + k0];
            acc[cf] = __builtin_amdgcn_mfma_f32_16x16x32_f16(bv, av, acc[cf], 0, 0, 0);
        }
    }
    float s1 = 0.f, s2 = 0.f;
    if (rok) {
#pragma unroll
        for (int cf = 0; cf < 8; ++cf) {
            int col = cf * 16 + g * 4;
            float4 gv = *(const float4*)&gf[(size_t)r * HID + col];
            s2 += acc[cf][0] * gv.x + acc[cf][1] * gv.y + acc[cf][2] * gv.z + acc[cf][3] * gv.w;
            s1 += sv[col] * gv.x + sv[col + 1] * gv.y + sv[col + 2] * gv.z + sv[col + 3] * gv.w;
        }
    }
    s1 += __shfl_xor(s1, 16); s1 += __shfl_xor(s1, 32);
    s2 += __shfl_xor(s2, 16); s2 += __shfl_xor(s2, 32);
    float l1 = 0.f, l2 = 0.f;
    if (g == 0 && rok) {
        float y = yv[r];
        float z1 = s1 + bctx[0];
        float z2 = s2 + bloc[0];
        l1 = fmaxf(z1, 0.f) + log1pf(expf(-fabsf(z1))) - z1 * y;
        l2 = fmaxf(z2, 0.f) + log1pf(expf(-fabsf(z2))) - z2 * (1.f - y);
    }
#pragma unroll
    for (int o = 1; o < 64; o <<= 1) {
        l1 += __shfl_xor(l1, o);
        l2 += __shfl_xor(l2, o);
    }
    if (lane == 0) {
        atomicAdd(&lsums[0], l1);
        atomicAdd(&lsums[1], l2);
    }
    __syncthreads();
    if (tid == 0) {
        __threadfence();
        int old = atomicAdd(donecnt, 1);
        if (old == nblk - 1) {
            float l1s = atomicAdd(&lsums[0], 0.f);
            float l2s = atomicAdd(&lsums[1], 0.f);
            float pc = pcnt_raw[0];
            float nc = (float)B - pc;
            float total = 0.5f * (l1s / (float)B) + 0.5f * (l2s / (float)B);
            out_loss[0] = (pc > 0.f && nc > 0.f) ? total : 0.f;
        }
    }
}

// ---------------- launcher ----------------

extern "C" void kernel_launch(void* const* d_in, const int* in_sizes, int n_in,
                              void* d_out, int out_size, void* d_ws, size_t ws_size,
                              hipStream_t stream) {
    const float* x      = (const float*)d_in[0];
    const int*   ei     = (const int*)d_in[1];
    const int*   batch  = (const int*)d_in[2];
    const int*   labels = (const int*)d_in[3];
    const float* W1     = (const float*)d_in[4];
    const float* b1     = (const float*)d_in[5];
    const float* W2     = (const float*)d_in[6];
    const float* b2     = (const float*)d_in[7];
    const float* Wctx   = (const float*)d_in[8];
    const float* bctx   = (const float*)d_in[9];
    const float* Wloc   = (const float*)d_in[10];
    const float* bloc   = (const float*)d_in[11];

    int N = in_sizes[0] / HID;
    int E = in_sizes[1] / 2;
    int B = in_sizes[2];
    float* out = (float*)d_out;

    char* wsb = (char*)d_ws;
    size_t off = 0;
    auto alloc = [&](size_t bytes) -> char* {
        char* p = wsb + off;
        off += (bytes + 255) & ~(size_t)255;
        return p;
    };
    int NB = ceil_div(N, 256);
    int mw = ceil_div(N, 32);

    _Float16* xs   = (_Float16*)alloc((size_t)(N + 1) * HID * 2);
    _Float16* H    = (_Float16*)alloc((size_t)(2 * N + 2) * HID * 2);
    unsigned int* ebuf = (unsigned int*)alloc((size_t)NB * CAP * 4);
    unsigned int* csr  = (unsigned int*)alloc((size_t)NB * CAP * 4);
    float* sdinv = (float*)alloc((size_t)N * 4);
    int*   rs    = (int*)alloc((size_t)N * 4);
    int*   degpk = (int*)alloc((size_t)N * 4);
    int*   bcur  = (int*)alloc((size_t)NB * 4);
    unsigned int* mask = (unsigned int*)alloc((size_t)mw * 4);
    _Float16* W1T = (_Float16*)alloc(128 * 128 * 2);
    _Float16* W2T = (_Float16*)alloc(128 * 128 * 2);
    _Float16* WlT = (_Float16*)alloc(128 * 128 * 2);
    _Float16* envh  = (_Float16*)alloc((size_t)B * HID * 2);
    float* yv    = (float*)alloc((size_t)B * 4);
    float* part  = (float*)alloc(128 * 4);
    float* pcnt_raw = (float*)alloc(256);
    float* lsums = (float*)alloc(256);
    int*   donecnt = (int*)alloc(256);
    (void)ws_size; (void)n_in; (void)out_size;

    int NBLKE = ceil_div(E, EPB);
    int NBLKB = ceil_div(B, 1024);
    int NHB = ceil_div(B, 64);

    k_setup<<<192 + ceil_div(mw, 256), 256, 0, stream>>>(W1, W2, Wloc, W1T, W2T, WlT, mask, bcur,
                                                         part, pcnt_raw, lsums, donecnt, mw, NB);
    k_partA<<<NBLKE + NBLKB, 1024, 0, stream>>>(ei, bcur, ebuf, batch, mask, E, B, NB, NBLKE);
    k_csr<<<NB, 256, 0, stream>>>(ebuf, bcur, mask, sdinv, rs, degpk, csr, N);
    k_cast<<<ceil_div(N * 16 + 48, 256), 256, 0, stream>>>(x, sdinv, xs, H, N);

    // fused layer 1 (512-thread / 32-node blocks)
    k_layer1<<<ceil_div(N, 32), 512, 0, stream>>>(xs, rs, degpk, csr, sdinv, W1T, b1, H, N);

    // fused layer 2 (512-thread / 16 batch rows, + pos-sum partials + yv)
    k_layer2<<<ceil_div(B, 16), 512, 0, stream>>>(H, rs, degpk, csr, sdinv, batch, labels, W2T, b2,
                                                  out, envh, yv, part, pcnt_raw, B, N);

    // fused heads (ctxvec + T + losses + final via last-block)
    k_headsT<<<NHB, 256, 0, stream>>>(envh, out, WlT, Wctx, part, pcnt_raw, yv, bctx, bloc,
                                      lsums, donecnt, out + (size_t)B * HID, B, NHB);
}